// Round 1
// baseline (484.088 us; speedup 1.0000x reference)
//
#include <hip/hip_runtime.h>
#include <hip/hip_bf16.h>

// VolatilityModulatedAttention: B=2, S=4096, H=512, NH=8, HD=64
//   scores = (Q K^T) / 8  -  lam*sigma_n*((i-j)/S)^2 ; attn = softmax; ctx = attn V
//   out = ctx @ W^T + b
// Strategy: bf16 MFMA flash attention (per-wave 16 q-rows, 64-key tiles) +
// bf16 MFMA projection GEMM. ctx staged in d_ws as bf16 [8192 x 512].

#define S_LEN 4096
#define NHEAD 8
#define HD 64
#define HTOT 512

typedef __attribute__((ext_vector_type(8))) short short8;
typedef __attribute__((ext_vector_type(4))) float floatx4;

__device__ __forceinline__ unsigned short f2bf(float x) {
    unsigned u = __builtin_bit_cast(unsigned, x);
    u += 0x7FFFu + ((u >> 16) & 1u);   // RNE
    return (unsigned short)(u >> 16);
}

// ---------------------------------------------------------------------------
// Flash attention. Grid: 1024 blocks = B(2) * NH(8) * (S/64=64 q-tiles).
// Block: 256 threads = 4 waves; wave w owns q rows [qbase + 16w, +16).
// ---------------------------------------------------------------------------
__global__ __launch_bounds__(256) void attn_kernel(
    const float* __restrict__ Q, const float* __restrict__ K,
    const float* __restrict__ V,
    const float* __restrict__ risk_sigma, const float* __restrict__ risk_lambda,
    unsigned short* __restrict__ ctx_bf16)
{
    // stride 72 shorts (144 B, 16B-multiple): b128 frag reads land 2-way (free)
    __shared__ unsigned short Qsh[64 * 72];
    __shared__ unsigned short Ksh[64 * 72];   // [key][d]
    __shared__ unsigned short Vsh[64 * 72];   // [d][key]  (transposed)
    __shared__ unsigned short Psh[4 * 16 * 72]; // per-wave P [q][key]

    const int tid  = threadIdx.x;
    const int wave = tid >> 6;
    const int lane = tid & 63;
    const int quad = lane >> 4;
    const int ln   = lane & 15;

    const int bid = blockIdx.x;
    const int qt  = bid & 63;
    const int h   = (bid >> 6) & 7;
    const int b   = bid >> 9;
    const int qbase = qt * 64;

    // risk coefficient: s = score*0.125 - coef*((i-j)/S)^2
    float sig = risk_sigma[b];
    sig = fminf(fmaxf(sig, 0.001f), 0.2f);
    const float sn   = (sig - 0.001f) * (1.0f / 0.199f);
    const float coef = risk_lambda[0] * 0.1f * sn;
    const float nc   = -coef * (1.0f / 4096.0f) * (1.0f / 4096.0f);
    const float scale = 0.125f;

    const float* Qb = Q + (size_t)b * S_LEN * HTOT + (size_t)h * HD;
    const float* Kb = K + (size_t)b * S_LEN * HTOT + (size_t)h * HD;
    const float* Vb = V + (size_t)b * S_LEN * HTOT + (size_t)h * HD;

    // ---- stage Q tile (64 rows x 64 d), fp32 -> bf16 LDS ----
    for (int i = 0; i < 4; i++) {
        int idx = tid + i * 256;       // 1024 float4 chunks
        int r = idx >> 4, c4 = idx & 15;
        float4 v = *(const float4*)(Qb + (size_t)(qbase + r) * HTOT + c4 * 4);
        unsigned w0 = f2bf(v.x) | ((unsigned)f2bf(v.y) << 16);
        unsigned w1 = f2bf(v.z) | ((unsigned)f2bf(v.w) << 16);
        unsigned* dst = (unsigned*)&Qsh[r * 72 + c4 * 4];
        dst[0] = w0; dst[1] = w1;
    }
    __syncthreads();

    // Q A-frags (held in registers all kernel): A[m=ln][k=quad*8+j]
    const short8 qf0 = *(const short8*)&Qsh[(wave * 16 + ln) * 72 + quad * 8];
    const short8 qf1 = *(const short8*)&Qsh[(wave * 16 + ln) * 72 + 32 + quad * 8];

    floatx4 Oacc[4];
    for (int n = 0; n < 4; n++) Oacc[n] = (floatx4){0.f, 0.f, 0.f, 0.f};
    float mrow[4], lrow[4];
    for (int r = 0; r < 4; r++) { mrow[r] = -INFINITY; lrow[r] = 0.f; }

    const int qa0 = qbase + wave * 16 + quad * 4;  // abs q row of reg 0

    for (int kt = 0; kt < S_LEN / 64; ++kt) {
        const int kbase = kt * 64;
        __syncthreads();  // previous iter's reads done before overwrite
        // ---- stage K (row-major) and V (transposed), fp32 -> bf16 ----
        for (int i = 0; i < 4; i++) {
            int idx = tid + i * 256;
            int r = idx >> 4, c4 = idx & 15;
            float4 kv = *(const float4*)(Kb + (size_t)(kbase + r) * HTOT + c4 * 4);
            unsigned w0 = f2bf(kv.x) | ((unsigned)f2bf(kv.y) << 16);
            unsigned w1 = f2bf(kv.z) | ((unsigned)f2bf(kv.w) << 16);
            unsigned* dst = (unsigned*)&Ksh[r * 72 + c4 * 4];
            dst[0] = w0; dst[1] = w1;
            float4 vv = *(const float4*)(Vb + (size_t)(kbase + r) * HTOT + c4 * 4);
            Vsh[(c4 * 4 + 0) * 72 + r] = f2bf(vv.x);
            Vsh[(c4 * 4 + 1) * 72 + r] = f2bf(vv.y);
            Vsh[(c4 * 4 + 2) * 72 + r] = f2bf(vv.z);
            Vsh[(c4 * 4 + 3) * 72 + r] = f2bf(vv.w);
        }
        __syncthreads();

        // ---- QK^T: S[16 q x 64 keys] in 4 C-frags ----
        floatx4 Sacc[4];
        for (int j = 0; j < 4; j++) {
            short8 bk0 = *(const short8*)&Ksh[(j * 16 + ln) * 72 + quad * 8];
            short8 bk1 = *(const short8*)&Ksh[(j * 16 + ln) * 72 + 32 + quad * 8];
            floatx4 a = (floatx4){0.f, 0.f, 0.f, 0.f};
            a = __builtin_amdgcn_mfma_f32_16x16x32_bf16(qf0, bk0, a, 0, 0, 0);
            a = __builtin_amdgcn_mfma_f32_16x16x32_bf16(qf1, bk1, a, 0, 0, 0);
            Sacc[j] = a;
        }

        // ---- bias + online softmax ----
        float sv[4][4], tmax[4];
        for (int r = 0; r < 4; r++) tmax[r] = -INFINITY;
        for (int j = 0; j < 4; j++) {
            int key = kbase + j * 16 + ln;
            for (int r = 0; r < 4; r++) {
                float diff = (float)(qa0 + r - key);
                float s = Sacc[j][r] * scale + nc * diff * diff;
                sv[j][r] = s;
                tmax[r] = fmaxf(tmax[r], s);
            }
        }
        for (int off = 8; off >= 1; off >>= 1)
            for (int r = 0; r < 4; r++)
                tmax[r] = fmaxf(tmax[r], __shfl_xor(tmax[r], off, 64));
        float alpha[4], mnew[4];
        for (int r = 0; r < 4; r++) {
            mnew[r] = fmaxf(mrow[r], tmax[r]);
            alpha[r] = __expf(mrow[r] - mnew[r]);   // exp(-inf)=0 on first tile
            mrow[r] = mnew[r];
        }
        float rsum[4] = {0.f, 0.f, 0.f, 0.f};
        for (int j = 0; j < 4; j++)
            for (int r = 0; r < 4; r++) {
                float p = __expf(sv[j][r] - mnew[r]);
                sv[j][r] = p;
                rsum[r] += p;
            }
        for (int off = 8; off >= 1; off >>= 1)
            for (int r = 0; r < 4; r++)
                rsum[r] += __shfl_xor(rsum[r], off, 64);
        for (int r = 0; r < 4; r++) lrow[r] = lrow[r] * alpha[r] + rsum[r];
        for (int n = 0; n < 4; n++)
            for (int r = 0; r < 4; r++)
                Oacc[n][r] *= alpha[r];

        // ---- P: C-layout -> LDS -> A-layout (per-wave region) ----
        unsigned short* Pw = &Psh[wave * 16 * 72];
        for (int j = 0; j < 4; j++)
            for (int r = 0; r < 4; r++)
                Pw[(quad * 4 + r) * 72 + j * 16 + ln] = f2bf(sv[j][r]);
        asm volatile("s_waitcnt lgkmcnt(0)" ::: "memory");
        __builtin_amdgcn_wave_barrier();
        short8 pf0 = *(const short8*)&Pw[ln * 72 + quad * 8];
        short8 pf1 = *(const short8*)&Pw[ln * 72 + 32 + quad * 8];

        // ---- PV: O[16 q x 64 d] += P[16 x 64keys] V[64keys x 64 d] ----
        for (int n = 0; n < 4; n++) {
            short8 bv0 = *(const short8*)&Vsh[(n * 16 + ln) * 72 + quad * 8];
            short8 bv1 = *(const short8*)&Vsh[(n * 16 + ln) * 72 + 32 + quad * 8];
            Oacc[n] = __builtin_amdgcn_mfma_f32_16x16x32_bf16(pf0, bv0, Oacc[n], 0, 0, 0);
            Oacc[n] = __builtin_amdgcn_mfma_f32_16x16x32_bf16(pf1, bv1, Oacc[n], 0, 0, 0);
        }
    }

    // ---- epilogue: ctx = O / l, store bf16 to workspace ----
    float rl[4];
    for (int r = 0; r < 4; r++) rl[r] = 1.0f / lrow[r];
    for (int n = 0; n < 4; n++)
        for (int r = 0; r < 4; r++) {
            int q = qa0 + r;
            int d = n * 16 + ln;
            ctx_bf16[((size_t)b * S_LEN + q) * HTOT + h * HD + d] =
                f2bf(Oacc[n][r] * rl[r]);
        }
}

// ---------------------------------------------------------------------------
// Projection GEMM: out[m][n] = sum_k ctx[m][k] * W[n][k] + bias[n]
// M=8192, N=512, K=512. 128x128 tile, BK=32, 4 waves (2x2) of 64x64.
// ---------------------------------------------------------------------------
__global__ __launch_bounds__(256) void proj_kernel(
    const unsigned short* __restrict__ A,  // ctx bf16 [8192 x 512]
    const float* __restrict__ W,           // [512 x 512] fp32
    const float* __restrict__ bias,        // [512]
    float* __restrict__ out)               // [8192 x 512] fp32
{
    __shared__ unsigned short Ash[128 * 40];
    __shared__ unsigned short Bsh[128 * 40];
    const int tid = threadIdx.x;
    const int wave = tid >> 6, lane = tid & 63, quad = lane >> 4, ln = lane & 15;
    const int wr = wave >> 1, wc = wave & 1;
    const int mblock = blockIdx.y * 128;
    const int nblock = blockIdx.x * 128;

    floatx4 acc[4][4];
    for (int i = 0; i < 4; i++)
        for (int j = 0; j < 4; j++) acc[i][j] = (floatx4){0.f, 0.f, 0.f, 0.f};

    for (int kt = 0; kt < 512 / 32; ++kt) {
        const int k0 = kt * 32;
        __syncthreads();
        // stage A tile (already bf16): 128 rows x 32 k = 512 chunks of 8 shorts
        for (int i = 0; i < 2; i++) {
            int idx = tid + i * 256;
            int r = idx >> 2, c8 = idx & 3;
            short8 v = *(const short8*)&A[(size_t)(mblock + r) * 512 + k0 + c8 * 8];
            *(short8*)&Ash[r * 40 + c8 * 8] = v;
        }
        // stage W tile fp32 -> bf16: 128 rows(n) x 32 k
        for (int i = 0; i < 4; i++) {
            int idx = tid + i * 256;
            int r = idx >> 3, c4 = idx & 7;
            float4 v = *(const float4*)&W[(size_t)(nblock + r) * 512 + k0 + c4 * 4];
            unsigned w0 = f2bf(v.x) | ((unsigned)f2bf(v.y) << 16);
            unsigned w1 = f2bf(v.z) | ((unsigned)f2bf(v.w) << 16);
            unsigned* dst = (unsigned*)&Bsh[r * 40 + c4 * 4];
            dst[0] = w0; dst[1] = w1;
        }
        __syncthreads();
        short8 af[4], bf[4];
        for (int i = 0; i < 4; i++)
            af[i] = *(const short8*)&Ash[(wr * 64 + i * 16 + ln) * 40 + quad * 8];
        for (int j = 0; j < 4; j++)
            bf[j] = *(const short8*)&Bsh[(wc * 64 + j * 16 + ln) * 40 + quad * 8];
        for (int i = 0; i < 4; i++)
            for (int j = 0; j < 4; j++)
                acc[i][j] = __builtin_amdgcn_mfma_f32_16x16x32_bf16(af[i], bf[j], acc[i][j], 0, 0, 0);
    }

    for (int i = 0; i < 4; i++) {
        int row = mblock + wr * 64 + i * 16 + quad * 4;
        for (int j = 0; j < 4; j++) {
            int col = nblock + wc * 64 + j * 16 + ln;
            float bv = bias[col];
            for (int r = 0; r < 4; r++)
                out[(size_t)(row + r) * 512 + col] = acc[i][j][r] + bv;
        }
    }
}

extern "C" void kernel_launch(void* const* d_in, const int* in_sizes, int n_in,
                              void* d_out, int out_size, void* d_ws, size_t ws_size,
                              hipStream_t stream) {
    const float* Q    = (const float*)d_in[0];
    const float* K    = (const float*)d_in[1];
    const float* V    = (const float*)d_in[2];
    const float* sig  = (const float*)d_in[3];
    const float* lam  = (const float*)d_in[4];
    const float* W    = (const float*)d_in[5];
    const float* bias = (const float*)d_in[6];
    unsigned short* ctx = (unsigned short*)d_ws;  // 8192*512 bf16 = 8 MB
    float* out = (float*)d_out;

    attn_kernel<<<dim3(1024), dim3(256), 0, stream>>>(Q, K, V, sig, lam, ctx);
    proj_kernel<<<dim3(4, 64), dim3(256), 0, stream>>>(ctx, W, bias, out);
}

// Round 2
// 266.482 us; speedup vs baseline: 1.8166x; 1.8166x over previous
//
#include <hip/hip_runtime.h>
#include <hip/hip_bf16.h>

// VolatilityModulatedAttention: B=2, S=4096, H=512, NH=8, HD=64
// Round 1: pre-converted bf16 K + pre-transposed bf16 V; fixed-max softmax
// (M=20, mathematically exact); deferred l reduction; 128 q-rows/block.

#define S_LEN 4096
#define NHEAD 8
#define HD 64
#define HTOT 512

typedef __attribute__((ext_vector_type(8))) short short8;
typedef __attribute__((ext_vector_type(4))) float floatx4;

__device__ __forceinline__ unsigned short f2bf(float x) {
    unsigned u = __builtin_bit_cast(unsigned, x);
    u += 0x7FFFu + ((u >> 16) & 1u);   // RNE
    return (unsigned short)(u >> 16);
}

// ---------------------------------------------------------------------------
// Pre-pass 1: K fp32 -> bf16, same [B,S,512] layout. 8 elems/thread.
// ---------------------------------------------------------------------------
__global__ __launch_bounds__(256) void k2bf_kernel(
    const float* __restrict__ K, unsigned short* __restrict__ K16)
{
    size_t i = ((size_t)blockIdx.x * 256 + threadIdx.x) * 8;
    float4 a = *(const float4*)(K + i);
    float4 b = *(const float4*)(K + i + 4);
    unsigned short o[8] = {f2bf(a.x), f2bf(a.y), f2bf(a.z), f2bf(a.w),
                           f2bf(b.x), f2bf(b.y), f2bf(b.z), f2bf(b.w)};
    *(short8*)(K16 + i) = *(short8*)o;
}

// ---------------------------------------------------------------------------
// Pre-pass 2: V fp32 [B,S,512] -> bf16 transposed per head Vt[B*8][64][4096].
// Grid: 1024 blocks = bh(16) x s-tile(64). 64 s x 64 d tile via LDS.
// ---------------------------------------------------------------------------
__global__ __launch_bounds__(256) void vtrans_kernel(
    const float* __restrict__ V, unsigned short* __restrict__ Vt)
{
    __shared__ unsigned short T[64 * 66];   // [d][s], pad 66
    const int tid = threadIdx.x;
    const int st = blockIdx.x & 63;
    const int bh = blockIdx.x >> 6;
    const int b = bh >> 3, h = bh & 7;
    const float* src = V + ((size_t)b * S_LEN + st * 64) * HTOT + h * HD;

    for (int i = 0; i < 4; i++) {
        int idx = tid + i * 256;            // 64 s-rows x 16 float4 chunks
        int s = idx >> 4, c4 = idx & 15;
        float4 v = *(const float4*)(src + (size_t)s * HTOT + c4 * 4);
        T[(c4 * 4 + 0) * 66 + s] = f2bf(v.x);
        T[(c4 * 4 + 1) * 66 + s] = f2bf(v.y);
        T[(c4 * 4 + 2) * 66 + s] = f2bf(v.z);
        T[(c4 * 4 + 3) * 66 + s] = f2bf(v.w);
    }
    __syncthreads();
    unsigned short* dst = Vt + ((size_t)bh * 64) * S_LEN + st * 64;
    for (int i = 0; i < 2; i++) {
        int idx = tid + i * 256;            // 64 d-rows x 8 short8 chunks
        int d = idx >> 3, c8 = idx & 7;
        short8 v = *(const short8*)&T[d * 66 + c8 * 8];
        *(short8*)(dst + (size_t)d * S_LEN + c8 * 8) = v;
    }
}

// ---------------------------------------------------------------------------
// Flash attention. Grid: 512 = B(2)*NH(8)*(S/128=32 q-tiles). Block: 4 waves,
// each wave owns 32 q rows (2 m-tiles of 16). Fixed-max softmax (M=20).
// ---------------------------------------------------------------------------
__global__ __launch_bounds__(256) void attn_kernel(
    const float* __restrict__ Q, const unsigned short* __restrict__ K16,
    const unsigned short* __restrict__ Vt,
    const float* __restrict__ risk_sigma, const float* __restrict__ risk_lambda,
    unsigned short* __restrict__ ctx_bf16)
{
    // QPsh: Q tile [128][72] during setup, then per-wave P [32][72] regions
    __shared__ unsigned short QPsh[128 * 72];   // 18432 B
    __shared__ unsigned short Ksh[64 * 72];     // [key][d]
    __shared__ unsigned short Vsh[64 * 72];     // [d][key]

    const int tid  = threadIdx.x;
    const int wave = tid >> 6;
    const int lane = tid & 63;
    const int quad = lane >> 4;
    const int ln   = lane & 15;

    const int bid = blockIdx.x;
    const int qt  = bid & 31;
    const int h   = (bid >> 5) & 7;
    const int b   = bid >> 8;
    const int qbase = qt * 128;

    float sig = risk_sigma[b];
    sig = fminf(fmaxf(sig, 0.001f), 0.2f);
    const float sn   = (sig - 0.001f) * (1.0f / 0.199f);
    const float coef = risk_lambda[0] * 0.1f * sn;
    const float nc   = -coef * (1.0f / 4096.0f) * (1.0f / 4096.0f);
    const float scale = 0.125f;
    const float M = 20.0f;   // fixed softmax reference (exact math)

    const float* Qb = Q + (size_t)b * S_LEN * HTOT + (size_t)h * HD;
    const unsigned short* Kb = K16 + (size_t)b * S_LEN * HTOT + (size_t)h * HD;
    const unsigned short* Vb = Vt + ((size_t)(b * 8 + h) * 64) * S_LEN;

    // ---- stage Q tile (128 x 64) fp32 -> bf16, one-time ----
    for (int i = 0; i < 8; i++) {
        int idx = tid + i * 256;            // 128 rows x 16 float4 chunks
        int r = idx >> 4, c4 = idx & 15;
        float4 v = *(const float4*)(Qb + (size_t)(qbase + r) * HTOT + c4 * 4);
        unsigned w0 = f2bf(v.x) | ((unsigned)f2bf(v.y) << 16);
        unsigned w1 = f2bf(v.z) | ((unsigned)f2bf(v.w) << 16);
        unsigned* dst = (unsigned*)&QPsh[r * 72 + c4 * 4];
        dst[0] = w0; dst[1] = w1;
    }
    __syncthreads();

    // Q A-frags: wave w, m-tile mt, rows qbase + w*32 + mt*16 + ln
    short8 qf[2][2];
    for (int mt = 0; mt < 2; mt++) {
        qf[mt][0] = *(const short8*)&QPsh[(wave * 32 + mt * 16 + ln) * 72 + quad * 8];
        qf[mt][1] = *(const short8*)&QPsh[(wave * 32 + mt * 16 + ln) * 72 + 32 + quad * 8];
    }
    // per-wave P region (aliases this wave's own Q rows — wave-private)
    unsigned short* Pw = &QPsh[wave * 32 * 72];

    floatx4 Oacc[2][4];
    float lpart[2][4];
    for (int mt = 0; mt < 2; mt++)
        for (int n = 0; n < 4; n++) Oacc[mt][n] = (floatx4){0.f, 0.f, 0.f, 0.f};
    for (int mt = 0; mt < 2; mt++)
        for (int r = 0; r < 4; r++) lpart[mt][r] = 0.f;

    const int qa = qbase + wave * 32;

    for (int kt = 0; kt < S_LEN / 64; ++kt) {
        const int kbase = kt * 64;
        __syncthreads();  // prev iter's K/V frag reads done before overwrite
        // ---- stage K [64 keys x 64 d] and V [64 d x 64 keys], bf16 copy ----
        for (int i = 0; i < 2; i++) {
            int idx = tid + i * 256;        // 64 rows x 8 short8 chunks
            int r = idx >> 3, c8 = idx & 7;
            short8 kv = *(const short8*)(Kb + (size_t)(kbase + r) * HTOT + c8 * 8);
            *(short8*)&Ksh[r * 72 + c8 * 8] = kv;
            short8 vv = *(const short8*)(Vb + (size_t)r * S_LEN + kbase + c8 * 8);
            *(short8*)&Vsh[r * 72 + c8 * 8] = vv;
        }
        __syncthreads();

        // ---- QK^T: 2 m-tiles x 64 keys ----
        floatx4 Sacc[2][4];
        for (int j = 0; j < 4; j++) {
            short8 bk0 = *(const short8*)&Ksh[(j * 16 + ln) * 72 + quad * 8];
            short8 bk1 = *(const short8*)&Ksh[(j * 16 + ln) * 72 + 32 + quad * 8];
            for (int mt = 0; mt < 2; mt++) {
                floatx4 a = (floatx4){0.f, 0.f, 0.f, 0.f};
                a = __builtin_amdgcn_mfma_f32_16x16x32_bf16(qf[mt][0], bk0, a, 0, 0, 0);
                a = __builtin_amdgcn_mfma_f32_16x16x32_bf16(qf[mt][1], bk1, a, 0, 0, 0);
                Sacc[mt][j] = a;
            }
        }

        // ---- fixed-max softmax: p = exp(s*scale + nc*diff^2 - M) ----
        for (int mt = 0; mt < 2; mt++) {
            float dm = (float)(qa + mt * 16 + quad * 4 - ln - kbase);
            for (int j = 0; j < 4; j++) {
                float d = dm - 16.0f * j;
                #pragma unroll
                for (int r = 0; r < 4; r++) {
                    float t = __builtin_fmaf(nc, d * d, -M);
                    float arg = __builtin_fmaf(Sacc[mt][j][r], scale, t);
                    float p = __expf(arg);
                    lpart[mt][r] += p;
                    Pw[(mt * 16 + quad * 4 + r) * 72 + j * 16 + ln] = f2bf(p);
                    d += 1.0f;
                }
            }
        }
        asm volatile("s_waitcnt lgkmcnt(0)" ::: "memory");
        __builtin_amdgcn_wave_barrier();

        // ---- PV: O += P[32 x 64keys] V[64keys x 64d] ----
        for (int mt = 0; mt < 2; mt++) {
            short8 pf0 = *(const short8*)&Pw[(mt * 16 + ln) * 72 + quad * 8];
            short8 pf1 = *(const short8*)&Pw[(mt * 16 + ln) * 72 + 32 + quad * 8];
            for (int n = 0; n < 4; n++) {
                short8 bv0 = *(const short8*)&Vsh[(n * 16 + ln) * 72 + quad * 8];
                short8 bv1 = *(const short8*)&Vsh[(n * 16 + ln) * 72 + 32 + quad * 8];
                Oacc[mt][n] = __builtin_amdgcn_mfma_f32_16x16x32_bf16(pf0, bv0, Oacc[mt][n], 0, 0, 0);
                Oacc[mt][n] = __builtin_amdgcn_mfma_f32_16x16x32_bf16(pf1, bv1, Oacc[mt][n], 0, 0, 0);
            }
        }
    }

    // ---- epilogue: reduce l across 16 lanes, ctx = O / l -> bf16 ----
    for (int mt = 0; mt < 2; mt++) {
        float rl[4];
        for (int r = 0; r < 4; r++) {
            float s = lpart[mt][r];
            for (int off = 8; off >= 1; off >>= 1)
                s += __shfl_xor(s, off, 64);
            rl[r] = 1.0f / s;
        }
        for (int n = 0; n < 4; n++)
            for (int r = 0; r < 4; r++) {
                int q = qa + mt * 16 + quad * 4 + r;
                int d = n * 16 + ln;
                ctx_bf16[((size_t)b * S_LEN + q) * HTOT + h * HD + d] =
                    f2bf(Oacc[mt][n][r] * rl[r]);
            }
    }
}

// ---------------------------------------------------------------------------
// Projection GEMM: out[m][n] = sum_k ctx[m][k] * W[n][k] + bias[n]
// ---------------------------------------------------------------------------
__global__ __launch_bounds__(256) void proj_kernel(
    const unsigned short* __restrict__ A,  // ctx bf16 [8192 x 512]
    const float* __restrict__ W,           // [512 x 512] fp32
    const float* __restrict__ bias,        // [512]
    float* __restrict__ out)               // [8192 x 512] fp32
{
    __shared__ unsigned short Ash[128 * 40];
    __shared__ unsigned short Bsh[128 * 40];
    const int tid = threadIdx.x;
    const int wave = tid >> 6, lane = tid & 63, quad = lane >> 4, ln = lane & 15;
    const int wr = wave >> 1, wc = wave & 1;
    const int mblock = blockIdx.y * 128;
    const int nblock = blockIdx.x * 128;

    floatx4 acc[4][4];
    for (int i = 0; i < 4; i++)
        for (int j = 0; j < 4; j++) acc[i][j] = (floatx4){0.f, 0.f, 0.f, 0.f};

    for (int kt = 0; kt < 512 / 32; ++kt) {
        const int k0 = kt * 32;
        __syncthreads();
        for (int i = 0; i < 2; i++) {
            int idx = tid + i * 256;
            int r = idx >> 2, c8 = idx & 3;
            short8 v = *(const short8*)&A[(size_t)(mblock + r) * 512 + k0 + c8 * 8];
            *(short8*)&Ash[r * 40 + c8 * 8] = v;
        }
        for (int i = 0; i < 4; i++) {
            int idx = tid + i * 256;
            int r = idx >> 3, c4 = idx & 7;
            float4 v = *(const float4*)&W[(size_t)(nblock + r) * 512 + k0 + c4 * 4];
            unsigned w0 = f2bf(v.x) | ((unsigned)f2bf(v.y) << 16);
            unsigned w1 = f2bf(v.z) | ((unsigned)f2bf(v.w) << 16);
            unsigned* dst = (unsigned*)&Bsh[r * 40 + c4 * 4];
            dst[0] = w0; dst[1] = w1;
        }
        __syncthreads();
        short8 af[4], bf[4];
        for (int i = 0; i < 4; i++)
            af[i] = *(const short8*)&Ash[(wr * 64 + i * 16 + ln) * 40 + quad * 8];
        for (int j = 0; j < 4; j++)
            bf[j] = *(const short8*)&Bsh[(wc * 64 + j * 16 + ln) * 40 + quad * 8];
        for (int i = 0; i < 4; i++)
            for (int j = 0; j < 4; j++)
                acc[i][j] = __builtin_amdgcn_mfma_f32_16x16x32_bf16(af[i], bf[j], acc[i][j], 0, 0, 0);
    }

    for (int i = 0; i < 4; i++) {
        int row = mblock + wr * 64 + i * 16 + quad * 4;
        for (int j = 0; j < 4; j++) {
            int col = nblock + wc * 64 + j * 16 + ln;
            float bv = bias[col];
            for (int r = 0; r < 4; r++)
                out[(size_t)(row + r) * 512 + col] = acc[i][j][r] + bv;
        }
    }
}

extern "C" void kernel_launch(void* const* d_in, const int* in_sizes, int n_in,
                              void* d_out, int out_size, void* d_ws, size_t ws_size,
                              hipStream_t stream) {
    const float* Q    = (const float*)d_in[0];
    const float* K    = (const float*)d_in[1];
    const float* V    = (const float*)d_in[2];
    const float* sig  = (const float*)d_in[3];
    const float* lam  = (const float*)d_in[4];
    const float* W    = (const float*)d_in[5];
    const float* bias = (const float*)d_in[6];

    unsigned short* ctx = (unsigned short*)d_ws;                 // 8 MB
    unsigned short* K16 = (unsigned short*)((char*)d_ws + (8u << 20));  // 8 MB
    unsigned short* Vt  = (unsigned short*)((char*)d_ws + (16u << 20)); // 8 MB
    float* out = (float*)d_out;

    k2bf_kernel<<<dim3(2048), dim3(256), 0, stream>>>(K, K16);
    vtrans_kernel<<<dim3(1024), dim3(256), 0, stream>>>(V, Vt);
    attn_kernel<<<dim3(512), dim3(256), 0, stream>>>(Q, K16, Vt, sig, lam, ctx);
    proj_kernel<<<dim3(4, 64), dim3(256), 0, stream>>>(ctx, W, bias, out);
}